// Round 10
// baseline (690.682 us; speedup 1.0000x reference)
//
#include <hip/hip_runtime.h>
#include <stdint.h>

// Problem: N=8, d=o=16, F=512, NUM_LAYERS=3.  ALL fp32 (per reference).
// out[n,o,g] = LN_o( 0.5*(c1 + c2) )  where
//   c0 = einsum(x, W, A0); h1 = LN_o(c0)
//   c1 = einsum(x, W, A1); c2 = einsum(h1, W, A0)
// einsum(h,W,a)[n,o,g] = sum_{d,f} h[n,d,f] * W[d,f,g,o] * a[f,g]
//
// R0-R9 findings:
//  - Every contract variant caps at ~150us per 256MB W pass (~1.7-2 TB/s),
//    invariant to: load width 4/8/16B, 1/2/4 cols/thr, W via reg/LDS, x via
//    s_load/LDS, occupancy 8-16 w/CU, strided vs sequential addressing (R7),
//    HALF THE BYTES via fp16 (R9 null) -> cap is not bytes, requests, LDS
//    ratio, or addressing. Cap currency unidentified from outside.
//  - Bookkeeping: contracts < 163us each (below fills in top-5) yet total
//    413us -> ~80-100us lives BETWEEN dispatches.
//  - Contracts never appear in top-5 -> no counters for them. Blind.
// R10: fuse everything into ONE kernel with device-scope spin barriers.
//  (a) kills inter-kernel gaps; (b) the fused kernel (>163us) is GUARANTEED
//  top-5 -> counters next round; (c) pass B serpentine (fl 31..0) harvests
//  pass A's L3-resident W tail; (d) fp32 both passes (fp16 reverted).
//  Deadlock-safe: 512 blocks, worst-case capacity 2 blocks/CU x 256 = 512.

#define FC   32    // f's per chunk
#define NCH  16    // 512 / FC
#define NBLK 512u  // grid size (must equal dim3(NCH,32) block count)

__global__ __launch_bounds__(256)
void k_fused(const float* __restrict__ W, const float* __restrict__ A,
             const float* __restrict__ x,
             float* __restrict__ c0p, float* __restrict__ c1p,
             float* __restrict__ c2p, float* __restrict__ out,
             unsigned* __restrict__ bar) {
    __shared__ float sx[FC][16][8];   // 16 KB: h slices [f_local][d][n]
    __shared__ float sA0[FC][16];     //  2 KB: A0 [f_local][g_local]
    __shared__ float sA1[FC][16];     //  2 KB: A1

    const int t  = threadIdx.x;       // 0..255
    const int fc = blockIdx.x;        // 0..15
    const int ct = blockIdx.y;        // 0..31
    const int f0 = fc * FC;

    // ================= phase A: c0 (A0) + c1 (A1) from x =================
    // transpose x slice into LDS (4096 vals, 16/thr); x is 256KB, L2/L3-hot
#pragma unroll
    for (int k = 0; k < 16; ++k) {
        int idx = k * 256 + t;
        int fl = idx >> 7, d = (idx >> 3) & 15, n = idx & 7;
        sx[fl][d][n] = x[n * 8192 + d * 512 + f0 + fl];
    }
#pragma unroll
    for (int k = 0; k < 2; ++k) {
        int idx = k * 256 + t;
        int fl = idx >> 4, gl = idx & 15;
        sA0[fl][gl] = A[(size_t)(f0 + fl) * 512 + ct * 16 + gl];
        sA1[fl][gl] = A[262144 + (size_t)(f0 + fl) * 512 + ct * 16 + gl];
    }
    __syncthreads();

    const int gl  = t >> 4;           // g_local 0..15
    const int col = ct * 256 + t;     // global column (g*16+o)
    const float* Wc = W + col;        // + d*4194304 + f*8192

    {
        float c0[8], c1[8];
#pragma unroll
        for (int n = 0; n < 8; ++n) { c0[n] = 0.f; c1[n] = 0.f; }

        for (int fl = 0; fl < FC; ++fl) {
            const int f = f0 + fl;
            float w[16];
#pragma unroll
            for (int d = 0; d < 16; ++d)
                w[d] = Wc[(size_t)d * 4194304 + (size_t)f * 8192];

            float p[8];
#pragma unroll
            for (int n = 0; n < 8; ++n) p[n] = 0.f;
#pragma unroll
            for (int d = 0; d < 16; ++d) {
                float4 xa = *reinterpret_cast<const float4*>(&sx[fl][d][0]);
                float4 xb = *reinterpret_cast<const float4*>(&sx[fl][d][4]);
                p[0] = fmaf(xa.x, w[d], p[0]);
                p[1] = fmaf(xa.y, w[d], p[1]);
                p[2] = fmaf(xa.z, w[d], p[2]);
                p[3] = fmaf(xa.w, w[d], p[3]);
                p[4] = fmaf(xb.x, w[d], p[4]);
                p[5] = fmaf(xb.y, w[d], p[5]);
                p[6] = fmaf(xb.z, w[d], p[6]);
                p[7] = fmaf(xb.w, w[d], p[7]);
            }
            const float a0 = sA0[fl][gl];
            const float a1 = sA1[fl][gl];
#pragma unroll
            for (int n = 0; n < 8; ++n) {
                c0[n] = fmaf(a0, p[n], c0[n]);
                c1[n] = fmaf(a1, p[n], c1[n]);
            }
        }
        size_t base = ((size_t)fc * 8192 + col) * 8;
        float4* dst0 = reinterpret_cast<float4*>(c0p + base);
        dst0[0] = make_float4(c0[0], c0[1], c0[2], c0[3]);
        dst0[1] = make_float4(c0[4], c0[5], c0[6], c0[7]);
        float4* dst1 = reinterpret_cast<float4*>(c1p + base);
        dst1[0] = make_float4(c1[0], c1[1], c1[2], c1[3]);
        dst1[1] = make_float4(c1[4], c1[5], c1[6], c1[7]);
    }

    // ---- grid barrier #1 (all c0 partials visible device-wide) ----
    __threadfence();
    __syncthreads();
    if (t == 0) {
        atomicAdd(&bar[0], 1u);
        while (atomicAdd(&bar[0], 0u) < NBLK) __builtin_amdgcn_s_sleep(2);
    }
    __syncthreads();
    __threadfence();

    // ============ phase B prologue: h1 rows f0..f0+31 into sx ============
    // reduce c0 partials over 16 chunks (4096 vals, 16/thr; 4MB buf, L2/L3)
#pragma unroll
    for (int k = 0; k < 16; ++k) {
        int idx = k * 256 + t;
        int fl = idx >> 7, o = (idx >> 3) & 15, n = idx & 7;
        float s = 0.f;
#pragma unroll
        for (int ch = 0; ch < NCH; ++ch)
            s += c0p[(((size_t)ch * 512 + f0 + fl) * 16 + o) * 8 + n];
        sx[fl][o][n] = s;
    }
    __syncthreads();
    // LayerNorm over o in place; thread owns (fl,n) -> exclusive column
    {
        int fl = t >> 3, n = t & 7;   // 32*8 = 256 = blockDim
        float m = 0.f, v = 0.f;
#pragma unroll
        for (int oo = 0; oo < 16; ++oo) { float y = sx[fl][oo][n]; m += y; v += y * y; }
        m *= (1.f / 16.f);
        v = v * (1.f / 16.f) - m * m;
        float r = rsqrtf(v + 1e-5f);
#pragma unroll
        for (int oo = 0; oo < 16; ++oo) sx[fl][oo][n] = (sx[fl][oo][n] - m) * r;
    }
    __syncthreads();

    // ================= phase B: c2 (A0) from h1, serpentine ==============
    {
        float c2[8];
#pragma unroll
        for (int n = 0; n < 8; ++n) c2[n] = 0.f;

        for (int s = 0; s < FC; ++s) {
            const int fl = FC - 1 - s;        // reverse order: L3 tail harvest
            const int f  = f0 + fl;
            float w[16];
#pragma unroll
            for (int d = 0; d < 16; ++d)
                w[d] = Wc[(size_t)d * 4194304 + (size_t)f * 8192];

            float p[8];
#pragma unroll
            for (int n = 0; n < 8; ++n) p[n] = 0.f;
#pragma unroll
            for (int d = 0; d < 16; ++d) {
                float4 xa = *reinterpret_cast<const float4*>(&sx[fl][d][0]);
                float4 xb = *reinterpret_cast<const float4*>(&sx[fl][d][4]);
                p[0] = fmaf(xa.x, w[d], p[0]);
                p[1] = fmaf(xa.y, w[d], p[1]);
                p[2] = fmaf(xa.z, w[d], p[2]);
                p[3] = fmaf(xa.w, w[d], p[3]);
                p[4] = fmaf(xb.x, w[d], p[4]);
                p[5] = fmaf(xb.y, w[d], p[5]);
                p[6] = fmaf(xb.z, w[d], p[6]);
                p[7] = fmaf(xb.w, w[d], p[7]);
            }
            const float a0 = sA0[fl][gl];
#pragma unroll
            for (int n = 0; n < 8; ++n) c2[n] = fmaf(a0, p[n], c2[n]);
        }
        size_t base = ((size_t)fc * 8192 + col) * 8;
        float4* dst = reinterpret_cast<float4*>(c2p + base);
        dst[0] = make_float4(c2[0], c2[1], c2[2], c2[3]);
        dst[1] = make_float4(c2[4], c2[5], c2[6], c2[7]);
    }

    // ---- grid barrier #2 (all c2 partials visible device-wide) ----
    __threadfence();
    __syncthreads();
    if (t == 0) {
        atomicAdd(&bar[1], 1u);
        while (atomicAdd(&bar[1], 0u) < NBLK) __builtin_amdgcn_s_sleep(2);
    }
    __syncthreads();
    __threadfence();

    // ====== phase C: y = 0.5*(c1+c2) reduced, LN over o, one g/block ======
    float* sh = &sA0[0][0];               // reuse 128 floats of dead LDS
    const int g = fc * 32 + ct;           // 0..511
    float sval = 0.f;
    if (t < 128) {
        int o = t >> 3, n = t & 7;
        float s0 = 0.f, s1 = 0.f;
#pragma unroll
        for (int ch = 0; ch < NCH; ++ch) {
            size_t idx = (((size_t)ch * 512 + g) * 16 + o) * 8 + n;
            s0 += c1p[idx];
            s1 += c2p[idx];
        }
        sval = 0.5f * (s0 + s1);
        sh[o * 8 + n] = sval;
    }
    __syncthreads();
    if (t < 128) {
        int o = t >> 3, n = t & 7;
        float m = 0.f, v = 0.f;
#pragma unroll
        for (int oo = 0; oo < 16; ++oo) { float y = sh[oo * 8 + n]; m += y; v += y * y; }
        m *= (1.f / 16.f);
        v = v * (1.f / 16.f) - m * m;
        float r = rsqrtf(v + 1e-5f);
        out[n * 8192 + o * 512 + g] = (sval - m) * r;
    }
}

extern "C" void kernel_launch(void* const* d_in, const int* in_sizes, int n_in,
                              void* d_out, int out_size, void* d_ws, size_t ws_size,
                              hipStream_t stream) {
    const float* x = (const float*)d_in[0];   // (8,16,512)      fp32
    const float* W = (const float*)d_in[1];   // (16,512,512,16) fp32
    const float* A = (const float*)d_in[2];   // (2,512,512)     fp32
    float* out = (float*)d_out;               // (8,16,512)      fp32

    float* ws  = (float*)d_ws;
    unsigned* bar = (unsigned*)d_ws;    // 2 counters at ws head
    float* c0p = ws + 256;              // 1048576 floats: c0 partials [16][8192][8]
    float* c1p = c0p + 1048576;         // 1048576 floats: c1 partials
    float* c2p = c1p + 1048576;         // 1048576 floats: c2 partials
    // total ws use: ~12.6 MB

    hipMemsetAsync(d_ws, 0, 2 * sizeof(unsigned), stream);  // zero barrier counters
    k_fused<<<dim3(NCH, 32), 256, 0, stream>>>(W, A, x, c0p, c1p, c2p, out, bar);
}

// Round 11
// 456.290 us; speedup vs baseline: 1.5137x; 1.5137x over previous
//
#include <hip/hip_runtime.h>
#include <stdint.h>

// Problem: N=8, d=o=16, F=512, NUM_LAYERS=3.  ALL fp32 (per reference).
// out[n,o,g] = LN_o( 0.5*(c1 + c2) )  where
//   c0 = einsum(x, W, A0); h1 = LN_o(c0)
//   c1 = einsum(x, W, A1); c2 = einsum(h1, W, A0)
// einsum(h,W,a)[n,o,g] = sum_{d,f} h[n,d,f] * W[d,f,g,o] * a[f,g]
//
// R10 counters (fused kernel, first direct observation): hbm 8% of peak,
// VALUBusy 6%, Occupancy 24%, FETCH 260MB/512MB logical (L3 serpentine
// works but doesn't speed pass B). => not BW-, not VALU-, not DRAM-bound;
// latency-bound with grid-capped occupancy: grid 512 = 2 blocks/CU was the
// cap in R4-R10. Fusion's spin barrier regressed dur (691 vs 433 kernel).
// R11: revert to R8 3-kernel structure (best, 413us) with two changes:
//  (1) grid 512 -> 1024 (FC 32->16): 4 blocks/CU = 16 waves/CU (VGPR ~85
//      fits the <=128 budget for 16 waves/CU; LDS 10.5KB x 4 = 42KB ok).
//  (2) explicit depth-1 W prefetch (w/wn double buffer): 16 loads stay in
//      flight during the FMA block instead of only during the vmcnt wait.

#define FC   16    // f's per chunk
#define NCH  32    // 512 / FC

// KA (SECOND=false): in = x (8,16,512); writes c0 partials (A0) + c1 (A1).
// KB (SECOND=true):  in = c0 partials; prologue reduces+LNs them into the
//                    16 h1 rows this block needs; writes c2 partials (A0).
// grid = (32 f-chunks, 32 col-tiles), 256 threads, 1 col/thread.
// Partial layout: [chunk][col][n], col = g*16+o.
template <bool SECOND>
__global__ __launch_bounds__(256)
void k_contract(const float* __restrict__ W, const float* __restrict__ A,
                const float* __restrict__ in,
                float* __restrict__ p0, float* __restrict__ p1) {
    __shared__ float sx[FC][16][8];   // 8 KB: h slices [f_local][d][n]
    __shared__ float sA0[FC][16];     // 1 KB
    __shared__ float sA1[FC][16];     // 1 KB (pass A only)

    const int t  = threadIdx.x;       // 0..255
    const int fc = blockIdx.x;        // 0..31
    const int ct = blockIdx.y;        // 0..31
    const int f0 = fc * FC;

    if constexpr (!SECOND) {
        // transpose x slice into LDS (2048 vals, 8/thr); x is 256KB, L2/L3-hot
#pragma unroll
        for (int k = 0; k < 8; ++k) {
            int idx = k * 256 + t;
            int fl = idx >> 7, d = (idx >> 3) & 15, n = idx & 7;
            sx[fl][d][n] = in[n * 8192 + d * 512 + f0 + fl];
        }
    } else {
        // reduce c0 partials over 32 chunks (2048 vals, 8/thr; 8MB, L2/L3-hot)
#pragma unroll
        for (int k = 0; k < 8; ++k) {
            int idx = k * 256 + t;
            int fl = idx >> 7, o = (idx >> 3) & 15, n = idx & 7;
            float s0 = 0.f, s1 = 0.f, s2 = 0.f, s3 = 0.f;
#pragma unroll
            for (int ch = 0; ch < NCH; ch += 4) {
                s0 += in[(((size_t)(ch + 0) * 512 + f0 + fl) * 16 + o) * 8 + n];
                s1 += in[(((size_t)(ch + 1) * 512 + f0 + fl) * 16 + o) * 8 + n];
                s2 += in[(((size_t)(ch + 2) * 512 + f0 + fl) * 16 + o) * 8 + n];
                s3 += in[(((size_t)(ch + 3) * 512 + f0 + fl) * 16 + o) * 8 + n];
            }
            sx[fl][o][n] = (s0 + s1) + (s2 + s3);
        }
        __syncthreads();
        // LayerNorm over o in place; thread (fl,n) owns column sx[fl][*][n]
        if (t < 128) {
            int fl = t >> 3, n = t & 7;           // 16 x 8 = 128
            float m = 0.f, v = 0.f;
#pragma unroll
            for (int oo = 0; oo < 16; ++oo) { float y = sx[fl][oo][n]; m += y; v += y * y; }
            m *= (1.f / 16.f);
            v = v * (1.f / 16.f) - m * m;
            float r = rsqrtf(v + 1e-5f);
#pragma unroll
            for (int oo = 0; oo < 16; ++oo) sx[fl][oo][n] = (sx[fl][oo][n] - m) * r;
        }
    }
    // stage A slices: FC*16 = 256 vals per mat, 1/thr
    {
        int fl = t >> 4, gl = t & 15;
        sA0[fl][gl] = A[(size_t)(f0 + fl) * 512 + ct * 16 + gl];
        if constexpr (!SECOND)
            sA1[fl][gl] = A[262144 + (size_t)(f0 + fl) * 512 + ct * 16 + gl];
    }
    __syncthreads();

    const int gl  = t >> 4;            // g_local 0..15
    const int col = ct * 256 + t;      // global column (g*16+o)
    const float* Wc = W + col;         // + d*4194304 + f*8192

    float c0[8], c1[8];
#pragma unroll
    for (int n = 0; n < 8; ++n) { c0[n] = 0.f; c1[n] = 0.f; }

    // depth-1 register double-buffer for the W column-slice
    float w[16], wn[16];
    auto FL = [&](int s) { return SECOND ? (FC - 1 - s) : s; };  // serpentine in B
    {
        const int f = f0 + FL(0);
#pragma unroll
        for (int d = 0; d < 16; ++d)
            w[d] = Wc[(size_t)d * 4194304 + (size_t)f * 8192];
    }

#pragma unroll
    for (int s = 0; s < FC; ++s) {
        const int fl = FL(s);
        // issue next slice's 16 loads BEFORE consuming w[]: they stay in
        // flight under this iteration's 128+ FMAs.
        if (s + 1 < FC) {
            const int fnext = f0 + FL(s + 1);
#pragma unroll
            for (int d = 0; d < 16; ++d)
                wn[d] = Wc[(size_t)d * 4194304 + (size_t)fnext * 8192];
        }

        float p[8];
#pragma unroll
        for (int n = 0; n < 8; ++n) p[n] = 0.f;
#pragma unroll
        for (int d = 0; d < 16; ++d) {
            float4 xa = *reinterpret_cast<const float4*>(&sx[fl][d][0]);
            float4 xb = *reinterpret_cast<const float4*>(&sx[fl][d][4]);
            p[0] = fmaf(xa.x, w[d], p[0]);
            p[1] = fmaf(xa.y, w[d], p[1]);
            p[2] = fmaf(xa.z, w[d], p[2]);
            p[3] = fmaf(xa.w, w[d], p[3]);
            p[4] = fmaf(xb.x, w[d], p[4]);
            p[5] = fmaf(xb.y, w[d], p[5]);
            p[6] = fmaf(xb.z, w[d], p[6]);
            p[7] = fmaf(xb.w, w[d], p[7]);
        }

        const float a0 = sA0[fl][gl];
#pragma unroll
        for (int n = 0; n < 8; ++n) c0[n] = fmaf(a0, p[n], c0[n]);
        if constexpr (!SECOND) {
            const float a1 = sA1[fl][gl];
#pragma unroll
            for (int n = 0; n < 8; ++n) c1[n] = fmaf(a1, p[n], c1[n]);
        }

        if (s + 1 < FC) {
#pragma unroll
            for (int d = 0; d < 16; ++d) w[d] = wn[d];   // register rename
        }
    }

    // partials [chunk][col][n]: thread's 8 floats contiguous, coalesced.
    size_t base = ((size_t)fc * 8192 + col) * 8;
    float4* dst0 = reinterpret_cast<float4*>(p0 + base);
    dst0[0] = make_float4(c0[0], c0[1], c0[2], c0[3]);
    dst0[1] = make_float4(c0[4], c0[5], c0[6], c0[7]);
    if constexpr (!SECOND) {
        float4* dst1 = reinterpret_cast<float4*>(p1 + base);
        dst1[0] = make_float4(c1[0], c1[1], c1[2], c1[3]);
        dst1[1] = make_float4(c1[4], c1[5], c1[6], c1[7]);
    }
}

// KF: y = 0.5*(c1+c2) reduced over 32 chunks, LayerNorm over o, out [n][o][g]
__global__ __launch_bounds__(128)
void k_final(const float* __restrict__ p1, const float* __restrict__ p2,
             float* __restrict__ out) {
    __shared__ float sh[16][8];
    int g = blockIdx.x;                 // 0..511
    int t = threadIdx.x;                // 0..127
    int o = t >> 3, n = t & 7;
    float s0 = 0.f, s1 = 0.f, s2 = 0.f, s3 = 0.f;
#pragma unroll
    for (int ch = 0; ch < NCH; ch += 2) {
        size_t i0 = (((size_t)(ch + 0) * 512 + g) * 16 + o) * 8 + n;
        size_t i1 = (((size_t)(ch + 1) * 512 + g) * 16 + o) * 8 + n;
        s0 += p1[i0]; s1 += p2[i0];
        s2 += p1[i1]; s3 += p2[i1];
    }
    float s = 0.5f * ((s0 + s1) + (s2 + s3));
    sh[o][n] = s;
    __syncthreads();
    float m = 0.f, v = 0.f;
#pragma unroll
    for (int oo = 0; oo < 16; ++oo) { float y = sh[oo][n]; m += y; v += y * y; }
    m *= (1.f / 16.f);
    v = v * (1.f / 16.f) - m * m;
    float r = rsqrtf(v + 1e-5f);
    out[n * 8192 + o * 512 + g] = (s - m) * r;
}

extern "C" void kernel_launch(void* const* d_in, const int* in_sizes, int n_in,
                              void* d_out, int out_size, void* d_ws, size_t ws_size,
                              hipStream_t stream) {
    const float* x = (const float*)d_in[0];   // (8,16,512)      fp32
    const float* W = (const float*)d_in[1];   // (16,512,512,16) fp32
    const float* A = (const float*)d_in[2];   // (2,512,512)     fp32
    float* out = (float*)d_out;               // (8,16,512)      fp32

    float* ws  = (float*)d_ws;
    float* c0p = ws;                    // 2097152 floats: c0 partials [32][8192][8]
    float* c1p = c0p + 2097152;         // 2097152 floats: c1 partials
    float* c2p = c1p + 2097152;         // 2097152 floats: c2 partials
    // total ws use: 24 MB

    k_contract<false><<<dim3(NCH, 32), 256, 0, stream>>>(W, A, x,   c0p, c1p);
    k_contract<true ><<<dim3(NCH, 32), 256, 0, stream>>>(W, A, c0p, c2p, nullptr);
    k_final<<<512, 128, 0, stream>>>(c1p, c2p, out);
}

// Round 12
// 414.592 us; speedup vs baseline: 1.6659x; 1.1006x over previous
//
#include <hip/hip_runtime.h>
#include <stdint.h>

// Problem: N=8, d=o=16, F=512, NUM_LAYERS=3.  ALL fp32 (per reference).
// out[n,o,g] = LN_o( 0.5*(c1 + c2) )  where
//   c0 = einsum(x, W, A0); h1 = LN_o(c0)
//   c1 = einsum(x, W, A1); c2 = einsum(h1, W, A0)
// einsum(h,W,a)[n,o,g] = sum_{d,f} h[n,d,f] * W[d,f,g,o] * a[f,g]
//
// R0-R11: every VGPR-load W feed caps at ~150us per 256MB pass (~2.8
// B/cyc/CU), invariant to bytes (fp16, R9), requests, addressing (R7),
// occupancy (R11), prefetch (R11), L3- vs HBM-source (R10: FETCH 260MB,
// pass B L3-served, same speed; VALU 6%, HBM 8%, occ 24% -> nothing busy).
// Hypothesis: per-CU vector-load RETURN path (VGPR writeback / miss queue)
// is the cap (~2-4 B/cyc/CU). The untested lever: global_load_lds DMA
// (no VGPR return; +35-67% over reg-staging in learn_hip m151/m193).
// R12 = R8 (best, 413us) with ONLY the W feed swapped: per-wave private
// 4KB double-buffered LDS slabs, 4 x global_load_lds(16B) per f-iter,
// counted vmcnt(4) (never 0 mid-loop), sched_barrier fences, no barriers.

#define FC   32    // f's per chunk
#define NCH  16    // 512 / FC

typedef const __attribute__((address_space(1))) uint32_t* gp1_t;
typedef __attribute__((address_space(3))) uint32_t* lp3_t;

__device__ __forceinline__ void gl_lds16(const void* g, void* l) {
    __builtin_amdgcn_global_load_lds((gp1_t)g, (lp3_t)l, 16, 0, 0);
}

// KA (SECOND=false): in = x (8,16,512); writes c0 partials (A0) + c1 (A1).
// KB (SECOND=true):  in = c0 partials; prologue reduces+LNs into the 32 h1
//                    rows this block needs; writes c2 partials (A0).
// grid = (16 f-chunks, 32 col-tiles), 256 threads, 1 col/thread.
// Partial layout: [chunk][col][n], col = g*16+o.
template <bool SECOND>
__global__ __launch_bounds__(256)
void k_contract(const float* __restrict__ W, const float* __restrict__ A,
                const float* __restrict__ in,
                float* __restrict__ p0, float* __restrict__ p1) {
    __shared__ float sx[FC][16][8];        // 16 KB: h slices [f_local][d][n]
    __shared__ float sA0[FC][16];          //  2 KB
    __shared__ float sA1[FC][16];          //  2 KB (pass A only)
    __shared__ float wbuf[2][4][16][64];   // 32 KB: [buf][wave][d][lane]

    const int t  = threadIdx.x;            // 0..255
    const int fc = blockIdx.x;             // 0..15
    const int ct = blockIdx.y;             // 0..31
    const int f0 = fc * FC;

    if constexpr (!SECOND) {
        // transpose x slice into LDS (4096 vals, 16/thr); x 256KB, L2/L3-hot
#pragma unroll
        for (int k = 0; k < 16; ++k) {
            int idx = k * 256 + t;
            int fl = idx >> 7, d = (idx >> 3) & 15, n = idx & 7;
            sx[fl][d][n] = in[n * 8192 + d * 512 + f0 + fl];
        }
    } else {
        // reduce c0 partials over 16 chunks (4096 vals, 16/thr; 4MB, L2/L3)
#pragma unroll
        for (int k = 0; k < 16; ++k) {
            int idx = k * 256 + t;
            int fl = idx >> 7, o = (idx >> 3) & 15, n = idx & 7;
            float s = 0.f;
#pragma unroll
            for (int ch = 0; ch < NCH; ++ch)
                s += in[(((size_t)ch * 512 + f0 + fl) * 16 + o) * 8 + n];
            sx[fl][o][n] = s;
        }
        __syncthreads();
        // LayerNorm over o in place; thread (fl,n) owns column sx[fl][*][n]
        {
            int fl = t >> 3, n = t & 7;    // 32*8 = 256 = blockDim
            float m = 0.f, v = 0.f;
#pragma unroll
            for (int oo = 0; oo < 16; ++oo) { float y = sx[fl][oo][n]; m += y; v += y * y; }
            m *= (1.f / 16.f);
            v = v * (1.f / 16.f) - m * m;
            float r = rsqrtf(v + 1e-5f);
#pragma unroll
            for (int oo = 0; oo < 16; ++oo) sx[fl][oo][n] = (sx[fl][oo][n] - m) * r;
        }
    }
    // stage A slices: 512 vals per mat, 2/thr
#pragma unroll
    for (int k = 0; k < 2; ++k) {
        int idx = k * 256 + t;
        int fl = idx >> 4, gl = idx & 15;
        sA0[fl][gl] = A[(size_t)(f0 + fl) * 512 + ct * 16 + gl];
        if constexpr (!SECOND)
            sA1[fl][gl] = A[262144 + (size_t)(f0 + fl) * 512 + ct * 16 + gl];
    }
    __syncthreads();   // also drains vmcnt -> clean slate for counted waits

    const int w  = t >> 6;                 // wave 0..3
    const int l  = t & 63;                 // lane
    const int gl = t >> 4;                 // g_local 0..15
    const int colbase = ct * 256 + w * 64; // wave's 64-col window
    const int col = colbase + l;

    // serpentine in pass B: harvest pass A's L3-resident tail
    auto FL = [&](int s) { return SECOND ? (FC - 1 - s) : s; };

    // stage one f-slab for this wave: 16 d x 64 cols x 4B = 4KB, 4 DMA ops.
    // instr k: lane l -> row d = 4k + (l>>4), cols (l&15)*4.. (+3).
    // LDS dest base wave-uniform; HW writes base + lane*16 (linear, m104).
    auto stage = [&](int s, int b) {
        const int f = f0 + FL(s);
#pragma unroll
        for (int k = 0; k < 4; ++k) {
            const float* g = W + (size_t)(4 * k + (l >> 4)) * 4194304
                               + (size_t)f * 8192 + colbase + (l & 15) * 4;
            gl_lds16(g, &wbuf[b][w][4 * k][0]);
        }
    };

    float c0[8], c1[8];
#pragma unroll
    for (int n = 0; n < 8; ++n) { c0[n] = 0.f; c1[n] = 0.f; }

    stage(0, 0);
    stage(1, 1);

#pragma unroll 2
    for (int s = 0; s < FC; ++s) {
        const int fl  = FL(s);
        const int cur = s & 1;

        // wait for buf[cur]'s 4 DMAs; keep buf[cur^1]'s 4 in flight (T4).
        if (s + 1 < FC) asm volatile("s_waitcnt vmcnt(4)" ::: "memory");
        else            asm volatile("s_waitcnt vmcnt(0)" ::: "memory");
        __builtin_amdgcn_sched_barrier(0);

        float p[8];
#pragma unroll
        for (int n = 0; n < 8; ++n) p[n] = 0.f;
#pragma unroll
        for (int d = 0; d < 16; ++d) {
            float wd  = wbuf[cur][w][d][l];            // ds_read_b32, conflict-free
            float4 xa = *reinterpret_cast<const float4*>(&sx[fl][d][0]);
            float4 xb = *reinterpret_cast<const float4*>(&sx[fl][d][4]);
            p[0] = fmaf(xa.x, wd, p[0]);
            p[1] = fmaf(xa.y, wd, p[1]);
            p[2] = fmaf(xa.z, wd, p[2]);
            p[3] = fmaf(xa.w, wd, p[3]);
            p[4] = fmaf(xb.x, wd, p[4]);
            p[5] = fmaf(xb.y, wd, p[5]);
            p[6] = fmaf(xb.z, wd, p[6]);
            p[7] = fmaf(xb.w, wd, p[7]);
        }

        const float a0 = sA0[fl][gl];
#pragma unroll
        for (int n = 0; n < 8; ++n) c0[n] = fmaf(a0, p[n], c0[n]);
        if constexpr (!SECOND) {
            const float a1 = sA1[fl][gl];
#pragma unroll
            for (int n = 0; n < 8; ++n) c1[n] = fmaf(a1, p[n], c1[n]);
        }

        // restage buf[cur] for f(s+2) AFTER its reads are consumed.
        if (s + 2 < FC) {
            __builtin_amdgcn_sched_barrier(0);
            stage(s + 2, cur);
        }
    }

    // partials [chunk][col][n]: thread's 8 floats contiguous, coalesced.
    size_t base = ((size_t)fc * 8192 + col) * 8;
    float4* dst0 = reinterpret_cast<float4*>(p0 + base);
    dst0[0] = make_float4(c0[0], c0[1], c0[2], c0[3]);
    dst0[1] = make_float4(c0[4], c0[5], c0[6], c0[7]);
    if constexpr (!SECOND) {
        float4* dst1 = reinterpret_cast<float4*>(p1 + base);
        dst1[0] = make_float4(c1[0], c1[1], c1[2], c1[3]);
        dst1[1] = make_float4(c1[4], c1[5], c1[6], c1[7]);
    }
}

// KF: y = 0.5*(c1+c2) reduced over 16 chunks, LayerNorm over o, out [n][o][g]
__global__ __launch_bounds__(128)
void k_final(const float* __restrict__ p1, const float* __restrict__ p2,
             float* __restrict__ out) {
    __shared__ float sh[16][8];
    int g = blockIdx.x;                 // 0..511
    int t = threadIdx.x;                // 0..127
    int o = t >> 3, n = t & 7;
    float s0 = 0.f, s1 = 0.f;
#pragma unroll
    for (int ch = 0; ch < NCH; ++ch) {
        size_t idx = (((size_t)ch * 512 + g) * 16 + o) * 8 + n;
        s0 += p1[idx];
        s1 += p2[idx];
    }
    float s = 0.5f * (s0 + s1);
    sh[o][n] = s;
    __syncthreads();
    float m = 0.f, v = 0.f;
#pragma unroll
    for (int oo = 0; oo < 16; ++oo) { float y = sh[oo][n]; m += y; v += y * y; }
    m *= (1.f / 16.f);
    v = v * (1.f / 16.f) - m * m;
    float r = rsqrtf(v + 1e-5f);
    out[n * 8192 + o * 512 + g] = (s - m) * r;
}

extern "C" void kernel_launch(void* const* d_in, const int* in_sizes, int n_in,
                              void* d_out, int out_size, void* d_ws, size_t ws_size,
                              hipStream_t stream) {
    const float* x = (const float*)d_in[0];   // (8,16,512)      fp32
    const float* W = (const float*)d_in[1];   // (16,512,512,16) fp32
    const float* A = (const float*)d_in[2];   // (2,512,512)     fp32
    float* out = (float*)d_out;               // (8,16,512)      fp32

    float* ws  = (float*)d_ws;
    float* c0p = ws;                    // 1048576 floats: c0 partials [16][8192][8]
    float* c1p = c0p + 1048576;         // 1048576 floats: c1 partials
    float* c2p = c1p + 1048576;         // 1048576 floats: c2 partials
    // total ws use: 12 MB

    k_contract<false><<<dim3(NCH, 32), 256, 0, stream>>>(W, A, x,   c0p, c1p);
    k_contract<true ><<<dim3(NCH, 32), 256, 0, stream>>>(W, A, c0p, c2p, nullptr);
    k_final<<<512, 128, 0, stream>>>(c1p, c2p, out);
}

// Round 13
// 409.503 us; speedup vs baseline: 1.6866x; 1.0124x over previous
//
#include <hip/hip_runtime.h>
#include <stdint.h>

// Problem: N=8, d=o=16, F=512, NUM_LAYERS=3.  ALL fp32 (per reference).
// out[n,o,g] = LN_o( 0.5*(c1 + c2) )  where
//   c0 = einsum(x, W, A0); h1 = LN_o(c0)
//   c1 = einsum(x, W, A1); c2 = einsum(h1, W, A0)
// einsum(h,W,a)[n,o,g] = sum_{d,f} h[n,d,f] * W[d,f,g,o] * a[f,g]
//
// R0-R12: ~150us per 256MB W pass (~1.7 TB/s) invariant to: feed mechanism
// (VGPR scalar loads / global_load_lds DMA / float4 stream), bytes (fp16),
// requests, addressing, occupancy, prefetch, barriers, L3-vs-HBM source.
// Three disjoint implementations within 2us of each other (413/414.6/417).
// Counters (R10): HBM 8%, VALU 6%, occ 24% -> unknown stall, no busy pipe.
// Last untested lever: CACHE-INSTALL path. Stream-once W installs 256MB
// into L1/L2/L3 twice per run; L2 (4MB/XCD) is fully thrashed. If the
// hidden serializer is the L2/L3 fill/install side of the return path
// (shared by normal loads AND global_load_lds -> explains R12 null; not
// paid by write-only fills -> explains 6.6 TB/s fills), nontemporal loads
// fix it. R13 = R8 (best) + nt on all W reads. x/A/partials stay cached.

#define FC   32    // f's per chunk
#define NCH  16    // 512 / FC

// KA (SECOND=false): in = x (8,16,512); writes c0 partials (A0) + c1 (A1).
// KB (SECOND=true):  in = c0 partials; prologue reduces+LNs into the 32 h1
//                    rows this block needs; writes c2 partials (A0).
// grid = (16 f-chunks, 32 col-tiles), 256 threads, 1 col/thread.
// Partial layout: [chunk][col][n], col = g*16+o.
template <bool SECOND>
__global__ __launch_bounds__(256)
void k_contract(const float* __restrict__ W, const float* __restrict__ A,
                const float* __restrict__ in,
                float* __restrict__ p0, float* __restrict__ p1) {
    __shared__ float sx[FC][16][8];   // 16 KB: h slices [f_local][d][n]
    __shared__ float sA0[FC][16];     //  2 KB: A0 [f_local][g_local]
    __shared__ float sA1[FC][16];     //  2 KB: A1 (pass A only)

    const int t  = threadIdx.x;       // 0..255
    const int fc = blockIdx.x;        // 0..15
    const int ct = blockIdx.y;        // 0..31
    const int f0 = fc * FC;

    if constexpr (!SECOND) {
        // transpose x slice into LDS (4096 vals, 16/thr); x 256KB, L2/L3-hot
#pragma unroll
        for (int k = 0; k < 16; ++k) {
            int idx = k * 256 + t;
            int fl = idx >> 7, d = (idx >> 3) & 15, n = idx & 7;
            sx[fl][d][n] = in[n * 8192 + d * 512 + f0 + fl];
        }
    } else {
        // reduce c0 partials over 16 chunks (4096 vals, 16/thr; 4MB, L2/L3)
#pragma unroll
        for (int k = 0; k < 16; ++k) {
            int idx = k * 256 + t;
            int fl = idx >> 7, o = (idx >> 3) & 15, n = idx & 7;
            float s = 0.f;
#pragma unroll
            for (int ch = 0; ch < NCH; ++ch)
                s += in[(((size_t)ch * 512 + f0 + fl) * 16 + o) * 8 + n];
            sx[fl][o][n] = s;
        }
        __syncthreads();
        // LayerNorm over o in place; thread (fl,n) owns column sx[fl][*][n]
        {
            int fl = t >> 3, n = t & 7;   // 32*8 = 256 = blockDim
            float m = 0.f, v = 0.f;
#pragma unroll
            for (int oo = 0; oo < 16; ++oo) { float y = sx[fl][oo][n]; m += y; v += y * y; }
            m *= (1.f / 16.f);
            v = v * (1.f / 16.f) - m * m;
            float r = rsqrtf(v + 1e-5f);
#pragma unroll
            for (int oo = 0; oo < 16; ++oo) sx[fl][oo][n] = (sx[fl][oo][n] - m) * r;
        }
    }
    // stage A slices: 512 vals per mat, 2/thr
#pragma unroll
    for (int k = 0; k < 2; ++k) {
        int idx = k * 256 + t;
        int fl = idx >> 4, gl = idx & 15;
        sA0[fl][gl] = A[(size_t)(f0 + fl) * 512 + ct * 16 + gl];
        if constexpr (!SECOND)
            sA1[fl][gl] = A[262144 + (size_t)(f0 + fl) * 512 + ct * 16 + gl];
    }
    __syncthreads();

    const int gl  = t >> 4;            // g_local 0..15
    const int col = ct * 256 + t;      // global column (g*16+o)
    const float* Wc = W + col;         // + d*4194304 + f*8192

    float c0[8], c1[8];
#pragma unroll
    for (int n = 0; n < 8; ++n) { c0[n] = 0.f; c1[n] = 0.f; }

    for (int s = 0; s < FC; ++s) {
        const int fl = SECOND ? (FC - 1 - s) : s;   // serpentine in pass B
        const int f  = f0 + fl;

        // NONTEMPORAL W loads: stream-once data, skip cache install.
        float w[16];
#pragma unroll
        for (int d = 0; d < 16; ++d)
            w[d] = __builtin_nontemporal_load(Wc + (size_t)d * 4194304 + (size_t)f * 8192);

        float p[8];
#pragma unroll
        for (int n = 0; n < 8; ++n) p[n] = 0.f;
#pragma unroll
        for (int d = 0; d < 16; ++d) {
            float4 xa = *reinterpret_cast<const float4*>(&sx[fl][d][0]);
            float4 xb = *reinterpret_cast<const float4*>(&sx[fl][d][4]);
            p[0] = fmaf(xa.x, w[d], p[0]);
            p[1] = fmaf(xa.y, w[d], p[1]);
            p[2] = fmaf(xa.z, w[d], p[2]);
            p[3] = fmaf(xa.w, w[d], p[3]);
            p[4] = fmaf(xb.x, w[d], p[4]);
            p[5] = fmaf(xb.y, w[d], p[5]);
            p[6] = fmaf(xb.z, w[d], p[6]);
            p[7] = fmaf(xb.w, w[d], p[7]);
        }

        const float a0 = sA0[fl][gl];
#pragma unroll
        for (int n = 0; n < 8; ++n) c0[n] = fmaf(a0, p[n], c0[n]);
        if constexpr (!SECOND) {
            const float a1 = sA1[fl][gl];
#pragma unroll
            for (int n = 0; n < 8; ++n) c1[n] = fmaf(a1, p[n], c1[n]);
        }
    }

    // partials [chunk][col][n]: thread's 8 floats contiguous, coalesced.
    size_t base = ((size_t)fc * 8192 + col) * 8;
    float4* dst0 = reinterpret_cast<float4*>(p0 + base);
    dst0[0] = make_float4(c0[0], c0[1], c0[2], c0[3]);
    dst0[1] = make_float4(c0[4], c0[5], c0[6], c0[7]);
    if constexpr (!SECOND) {
        float4* dst1 = reinterpret_cast<float4*>(p1 + base);
        dst1[0] = make_float4(c1[0], c1[1], c1[2], c1[3]);
        dst1[1] = make_float4(c1[4], c1[5], c1[6], c1[7]);
    }
}

// KF: y = 0.5*(c1+c2) reduced over 16 chunks, LayerNorm over o, out [n][o][g]
__global__ __launch_bounds__(128)
void k_final(const float* __restrict__ p1, const float* __restrict__ p2,
             float* __restrict__ out) {
    __shared__ float sh[16][8];
    int g = blockIdx.x;                 // 0..511
    int t = threadIdx.x;                // 0..127
    int o = t >> 3, n = t & 7;
    float s0 = 0.f, s1 = 0.f;
#pragma unroll
    for (int ch = 0; ch < NCH; ++ch) {
        size_t idx = (((size_t)ch * 512 + g) * 16 + o) * 8 + n;
        s0 += p1[idx];
        s1 += p2[idx];
    }
    float s = 0.5f * (s0 + s1);
    sh[o][n] = s;
    __syncthreads();
    float m = 0.f, v = 0.f;
#pragma unroll
    for (int oo = 0; oo < 16; ++oo) { float y = sh[oo][n]; m += y; v += y * y; }
    m *= (1.f / 16.f);
    v = v * (1.f / 16.f) - m * m;
    float r = rsqrtf(v + 1e-5f);
    out[n * 8192 + o * 512 + g] = (s - m) * r;
}

extern "C" void kernel_launch(void* const* d_in, const int* in_sizes, int n_in,
                              void* d_out, int out_size, void* d_ws, size_t ws_size,
                              hipStream_t stream) {
    const float* x = (const float*)d_in[0];   // (8,16,512)      fp32
    const float* W = (const float*)d_in[1];   // (16,512,512,16) fp32
    const float* A = (const float*)d_in[2];   // (2,512,512)     fp32
    float* out = (float*)d_out;               // (8,16,512)      fp32

    float* ws  = (float*)d_ws;
    float* c0p = ws;                    // 1048576 floats: c0 partials [16][8192][8]
    float* c1p = c0p + 1048576;         // 1048576 floats: c1 partials
    float* c2p = c1p + 1048576;         // 1048576 floats: c2 partials
    // total ws use: 12 MB

    k_contract<false><<<dim3(NCH, 32), 256, 0, stream>>>(W, A, x,   c0p, c1p);
    k_contract<true ><<<dim3(NCH, 32), 256, 0, stream>>>(W, A, c0p, c2p, nullptr);
    k_final<<<512, 128, 0, stream>>>(c1p, c2p, out);
}